// Round 1
// baseline (2003.276 us; speedup 1.0000x reference)
//
#include <hip/hip_runtime.h>
#include <hip/hip_bf16.h>

#define H 128
#define RBF 64

// ---------------------------------------------------------------- utilities
// LN over a 128-wide row, one row per 128-thread block.
__global__ __launch_bounds__(128) void ln_rows(const float* __restrict__ X,
                                               const float* __restrict__ g,
                                               const float* __restrict__ bb,
                                               float* __restrict__ Y, int N) {
  __shared__ float sh[4];
  const int row = blockIdx.x;
  const int j = threadIdx.x;
  float x = X[(size_t)row * H + j];
  float s = x, q = x * x;
#pragma unroll
  for (int m = 32; m; m >>= 1) {
    s += __shfl_xor(s, m, 64);
    q += __shfl_xor(q, m, 64);
  }
  if ((j & 63) == 0) { sh[(j >> 6) * 2] = s; sh[(j >> 6) * 2 + 1] = q; }
  __syncthreads();
  s = sh[0] + sh[2];
  q = sh[1] + sh[3];
  const float mu = s * 0.0078125f;
  const float var = q * 0.0078125f - mu * mu;
  const float rs = rsqrtf(var + 1e-5f);
  Y[(size_t)row * H + j] = (x - mu) * rs * g[j] + bb[j];
}

// out = base + LN(S; g,b) + skip, row-wise.
__global__ __launch_bounds__(128) void final_add(const float* __restrict__ base,
                                                 const float* __restrict__ skip,
                                                 const float* __restrict__ S,
                                                 const float* __restrict__ g,
                                                 const float* __restrict__ bb,
                                                 float* __restrict__ out, int N) {
  __shared__ float sh[4];
  const int row = blockIdx.x;
  const int j = threadIdx.x;
  const size_t idx = (size_t)row * H + j;
  float x = S[idx];
  float s = x, q = x * x;
#pragma unroll
  for (int m = 32; m; m >>= 1) {
    s += __shfl_xor(s, m, 64);
    q += __shfl_xor(q, m, 64);
  }
  if ((j & 63) == 0) { sh[(j >> 6) * 2] = s; sh[(j >> 6) * 2 + 1] = q; }
  __syncthreads();
  s = sh[0] + sh[2];
  q = sh[1] + sh[3];
  const float mu = s * 0.0078125f;
  const float var = q * 0.0078125f - mu * mu;
  const float rs = rsqrtf(var + 1e-5f);
  out[idx] = base[idx] + ((x - mu) * rs * g[j] + bb[j]) + skip[idx];
}

// conv_k (o,i,dx,dy,dz) -> Kt[tap][i][o]
__global__ void transpose_k(const float* __restrict__ K, float* __restrict__ Kt) {
  const int idx = blockIdx.x * 256 + threadIdx.x;
  const int total = H * H * 27;
  if (idx >= total) return;
  const int tap = idx % 27;
  const int rem = idx / 27;
  const int i = rem % H;
  const int o = rem / H;
  Kt[((size_t)tap * H + i) * H + o] = K[idx];
}

// ------------------------------------------- node projection: Y = [LN](X) @ W
// block 256, tile = 64 rows x 128 cols. A-tile transposed in LDS (stride 68),
// W read from global (L2-resident, 64KB reused by every block).
template <bool DO_LN>
__global__ __launch_bounds__(256) void proj_kernel(const float* __restrict__ X,
                                                   const float* __restrict__ W,
                                                   const float* __restrict__ g,
                                                   const float* __restrict__ bb,
                                                   float* __restrict__ Y, int N) {
  __shared__ float At[128 * 68];
  const int row0 = blockIdx.x * 64;
  const int t = threadIdx.x;
  const int lk = (t & 31) * 4;  // k-column start for staging
  const int lr = t >> 5;        // row sub-index (0..7)
  float4 g4 = {0, 0, 0, 0}, b4 = {0, 0, 0, 0};
  if (DO_LN) {
    g4 = *(const float4*)(g + lk);
    b4 = *(const float4*)(bb + lk);
  }
#pragma unroll
  for (int p = 0; p < 8; ++p) {
    const int r = lr + p * 8;  // 0..63
    const int row = row0 + r;
    float4 xv = make_float4(0.f, 0.f, 0.f, 0.f);
    if (row < N) xv = *(const float4*)(X + (size_t)row * H + lk);
    if (DO_LN) {
      float s = xv.x + xv.y + xv.z + xv.w;
      float q = xv.x * xv.x + xv.y * xv.y + xv.z * xv.z + xv.w * xv.w;
#pragma unroll
      for (int m = 16; m; m >>= 1) {  // 32 lanes share one row
        s += __shfl_xor(s, m, 64);
        q += __shfl_xor(q, m, 64);
      }
      const float mu = s * 0.0078125f;
      const float var = q * 0.0078125f - mu * mu;
      const float rs = rsqrtf(var + 1e-5f);
      xv.x = (xv.x - mu) * rs * g4.x + b4.x;
      xv.y = (xv.y - mu) * rs * g4.y + b4.y;
      xv.z = (xv.z - mu) * rs * g4.z + b4.z;
      xv.w = (xv.w - mu) * rs * g4.w + b4.w;
    }
    At[(lk + 0) * 68 + r] = xv.x;
    At[(lk + 1) * 68 + r] = xv.y;
    At[(lk + 2) * 68 + r] = xv.z;
    At[(lk + 3) * 68 + r] = xv.w;
  }
  __syncthreads();
  const int tc = t & 15;  // 8 output cols
  const int tr = t >> 4;  // 4 rows
  float acc[4][8];
#pragma unroll
  for (int i = 0; i < 4; ++i)
#pragma unroll
    for (int c = 0; c < 8; ++c) acc[i][c] = 0.f;
  const float* wbase = W + tc * 8;
#pragma unroll 4
  for (int k = 0; k < 128; ++k) {
    const float4 a4 = *(const float4*)(At + k * 68 + tr * 4);
    const float4 w0 = *(const float4*)(wbase + k * H);
    const float4 w1 = *(const float4*)(wbase + k * H + 4);
    const float av[4] = {a4.x, a4.y, a4.z, a4.w};
#pragma unroll
    for (int i = 0; i < 4; ++i) {
      acc[i][0] += av[i] * w0.x; acc[i][1] += av[i] * w0.y;
      acc[i][2] += av[i] * w0.z; acc[i][3] += av[i] * w0.w;
      acc[i][4] += av[i] * w1.x; acc[i][5] += av[i] * w1.y;
      acc[i][6] += av[i] * w1.z; acc[i][7] += av[i] * w1.w;
    }
  }
#pragma unroll
  for (int i = 0; i < 4; ++i) {
    const int row = row0 + tr * 4 + i;
    if (row < N) {
      float4 o0 = {acc[i][0], acc[i][1], acc[i][2], acc[i][3]};
      float4 o1 = {acc[i][4], acc[i][5], acc[i][6], acc[i][7]};
      float* yp = Y + (size_t)row * H + tc * 8;
      *(float4*)yp = o0;
      *(float4*)(yp + 4) = o1;
    }
  }
}

// ------------------------------------------------------- fused edge scatter
// msg_e = P[src_e] * (ea_e @ We) * w_e ; atomicAdd into out[dst_e].
// Wave-per-edge-stream; lane owns one column; 64 We coefficients in VGPRs;
// edge-uniform data through SGPRs (readfirstlane -> s_load).
__global__ __launch_bounds__(256) void edge_scatter(const float* __restrict__ P,
                                                    const int* __restrict__ src,
                                                    const int* __restrict__ dst,
                                                    const float* __restrict__ ew,
                                                    const float* __restrict__ ea,
                                                    const float* __restrict__ We,
                                                    float* __restrict__ out, int E) {
  const int lane = threadIdx.x & 63;
  const int wv = threadIdx.x >> 6;      // wave in block (0..3)
  const int col = (wv & 1) * 64 + lane; // column half per wave
  float we[RBF];
#pragma unroll
  for (int k = 0; k < RBF; ++k) we[k] = We[k * H + col];
  const int stream = blockIdx.x * 2 + (wv >> 1);
  const int estep = gridDim.x * 2;
  for (int e0 = stream; e0 < E; e0 += estep) {
    const int e = __builtin_amdgcn_readfirstlane(e0);  // wave-uniform -> SGPR
    const float* eap = ea + (size_t)e * RBF;
    float f = 0.f;
#pragma unroll
    for (int k = 0; k < RBF; ++k) f += eap[k] * we[k];
    const int s = src[e];
    const int d = dst[e];
    const float m = P[(size_t)s * H + col] * f * ew[e];
    atomicAdd(out + (size_t)d * H + col, m);
  }
}

// ----------------------------------------------------------------- conv3d
// One (batch, x)-slab of 64 voxels per block; 3 x-slices staged in LDS in two
// 64-channel passes; weights from pre-transposed Kt (L2-resident).
__global__ __launch_bounds__(256) void conv3d(const float* __restrict__ Min,
                                              const float* __restrict__ Kt,
                                              const float* __restrict__ bias,
                                              float* __restrict__ Mout) {
  __shared__ float in_s[193 * 68];  // 192 rows + zero row, 64ch, pad->68
  const int b = blockIdx.x >> 3;
  const int x = blockIdx.x & 7;
  const int t = threadIdx.x;
  const int tc = t & 15;  // 8 output channels
  const int tr = t >> 4;  // 4 voxels
  float acc[4][8];
  {
    const float4 bs0 = *(const float4*)(bias + tc * 8);
    const float4 bs1 = *(const float4*)(bias + tc * 8 + 4);
#pragma unroll
    for (int vi = 0; vi < 4; ++vi) {
      acc[vi][0] = bs0.x; acc[vi][1] = bs0.y; acc[vi][2] = bs0.z; acc[vi][3] = bs0.w;
      acc[vi][4] = bs1.x; acc[vi][5] = bs1.y; acc[vi][6] = bs1.z; acc[vi][7] = bs1.w;
    }
  }
  for (int u = t; u < 68; u += 256) in_s[192 * 68 + u] = 0.f;  // zero row

  for (int pass = 0; pass < 2; ++pass) {
    __syncthreads();
    // stage 192 rows x 64 channels
#pragma unroll
    for (int it = 0; it < 12; ++it) {
      const int r = (t >> 4) + it * 16;  // 0..191
      const int c4 = (t & 15) * 4;
      const int xs = r >> 6;
      const int yz = r & 63;
      const int gx = x + xs - 1;
      float4 val = make_float4(0.f, 0.f, 0.f, 0.f);
      if (gx >= 0 && gx < 8) {
        const int row = (b * 8 + gx) * 64 + yz;
        val = *(const float4*)(Min + (size_t)row * H + pass * 64 + c4);
      }
      *(float4*)(in_s + r * 68 + c4) = val;
    }
    __syncthreads();

    for (int tap = 0; tap < 27; ++tap) {
      const int dx = tap / 9, dy = (tap / 3) % 3, dz = tap % 3;
      int rp[4];
#pragma unroll
      for (int vi = 0; vi < 4; ++vi) {
        const int v = tr * 4 + vi;
        const int y = v >> 3, z = v & 7;
        const int ny = y + dy - 1, nz = z + dz - 1;
        const bool ok = (ny >= 0 && ny < 8 && nz >= 0 && nz < 8);
        rp[vi] = ok ? (dx * 64 + ny * 8 + nz) * 68 : 192 * 68;
      }
      const float* wbase = Kt + ((size_t)tap * H + pass * 64) * H + tc * 8;
#pragma unroll 4
      for (int kk = 0; kk < 64; ++kk) {
        const float4 w0 = *(const float4*)(wbase + (size_t)kk * H);
        const float4 w1 = *(const float4*)(wbase + (size_t)kk * H + 4);
        float iv[4];
#pragma unroll
        for (int vi = 0; vi < 4; ++vi) iv[vi] = in_s[rp[vi] + kk];
#pragma unroll
        for (int vi = 0; vi < 4; ++vi) {
          acc[vi][0] += iv[vi] * w0.x; acc[vi][1] += iv[vi] * w0.y;
          acc[vi][2] += iv[vi] * w0.z; acc[vi][3] += iv[vi] * w0.w;
          acc[vi][4] += iv[vi] * w1.x; acc[vi][5] += iv[vi] * w1.y;
          acc[vi][6] += iv[vi] * w1.z; acc[vi][7] += iv[vi] * w1.w;
        }
      }
    }
  }
#pragma unroll
  for (int vi = 0; vi < 4; ++vi) {
    const int v = tr * 4 + vi;
    float* op = Mout + ((size_t)((b * 8 + x) * 64 + v)) * H + tc * 8;
    float4 o0 = {acc[vi][0], acc[vi][1], acc[vi][2], acc[vi][3]};
    float4 o1 = {acc[vi][4], acc[vi][5], acc[vi][6], acc[vi][7]};
    *(float4*)op = o0;
    *(float4*)(op + 4) = o1;
  }
}

// ------------------------------------------------------------------ driver
extern "C" void kernel_launch(void* const* d_in, const int* in_sizes, int n_in,
                              void* d_out, int out_size, void* d_ws, size_t ws_size,
                              hipStream_t stream) {
  const float* a_x = (const float*)d_in[0];
  const float* m_x = (const float*)d_in[1];
  const int* aa_idx = (const int*)d_in[2];
  const int* a2m_src = (const int*)d_in[3];
  const int* a2m_dst = (const int*)d_in[4];
  const int* m2a_src = (const int*)d_in[5];
  const int* m2a_dst = (const int*)d_in[6];
  const float* aa_w = (const float*)d_in[7];
  const float* a2m_w = (const float*)d_in[8];
  const float* m2a_w = (const float*)d_in[9];
  const float* aa_ea = (const float*)d_in[10];
  const float* a2m_ea = (const float*)d_in[11];
  const float* m2a_ea = (const float*)d_in[12];
  const float* W_short = (const float*)d_in[13];
  const float* We_short = (const float*)d_in[14];
  const float* W_a2m = (const float*)d_in[15];
  const float* We_a2m = (const float*)d_in[16];
  const float* W_m2a = (const float*)d_in[17];
  const float* We_m2a = (const float*)d_in[18];
  const float* conv_k = (const float*)d_in[19];
  const float* conv_b = (const float*)d_in[20];
  const float* g_short = (const float*)d_in[21];
  const float* b_short = (const float*)d_in[22];
  const float* g_long = (const float*)d_in[23];
  const float* b_long = (const float*)d_in[24];
  const float* g_a2m = (const float*)d_in[25];
  const float* b_a2m = (const float*)d_in[26];
  const float* g_m2a = (const float*)d_in[27];
  const float* b_m2a = (const float*)d_in[28];

  const int NA = in_sizes[0] / H;     // 50000
  const int NM = in_sizes[1] / H;     // 16384
  const int E_AA = in_sizes[2] / 2;   // 800000
  const int E_AM = in_sizes[3];       // 400000
  const int E_MA = in_sizes[5];       // 400000
  const int* aa_src = aa_idx;
  const int* aa_dst = aa_idx + E_AA;

  float* ws = (float*)d_ws;
  float* p_buf = ws;                          // NA*H : P_short, later P_a2m
  float* m1_buf = p_buf + (size_t)NA * H;     // NM*H : LN(m_x), later P_m2a
  float* m2_buf = m1_buf + (size_t)NM * H;    // NM*H : conv output
  float* a2_buf = m2_buf + (size_t)NM * H;    // NA*H : a2a scatter out
  float* sa2m = a2_buf + (size_t)NA * H;      // NM*H : a2m scatter out
  float* sm2a = sa2m + (size_t)NM * H;        // NA*H : m2a scatter out
  float* kt = sm2a + (size_t)NA * H;          // 27*128*128

  float* out_a = (float*)d_out;
  float* out_m = out_a + (size_t)NA * H;

  // zero the atomic accumulators
  hipMemsetAsync(a2_buf, 0, (size_t)NA * H * sizeof(float), stream);
  hipMemsetAsync(sa2m, 0, (size_t)NM * H * sizeof(float), stream);
  hipMemsetAsync(sm2a, 0, (size_t)NA * H * sizeof(float), stream);

  // conv weight transpose
  transpose_k<<<(H * H * 27 + 255) / 256, 256, 0, stream>>>(conv_k, kt);

  // m1 = LN(m_x)
  ln_rows<<<NM, 128, 0, stream>>>(m_x, g_long, b_long, m1_buf, NM);

  // P_short = LN(a_x) @ W_short
  proj_kernel<true><<<(NA + 63) / 64, 256, 0, stream>>>(a_x, W_short, g_short,
                                                        b_short, p_buf, NA);
  // a2 = scatter_aa(P_short)
  edge_scatter<<<1024, 256, 0, stream>>>(p_buf, aa_src, aa_dst, aa_w, aa_ea,
                                         We_short, a2_buf, E_AA);
  // m2 = conv3d(m1)
  conv3d<<<(NM / 64), 256, 0, stream>>>(m1_buf, kt, conv_b, m2_buf);

  // P_a2m = a2 @ W_a2m  (reuse p_buf)
  proj_kernel<false><<<(NA + 63) / 64, 256, 0, stream>>>(a2_buf, W_a2m, nullptr,
                                                         nullptr, p_buf, NA);
  // s_a2m = scatter_a2m(P_a2m)
  edge_scatter<<<1024, 256, 0, stream>>>(p_buf, a2m_src, a2m_dst, a2m_w, a2m_ea,
                                         We_a2m, sa2m, E_AM);
  // P_m2a = m2 @ W_m2a  (reuse m1_buf)
  proj_kernel<false><<<(NM + 63) / 64, 256, 0, stream>>>(m2_buf, W_m2a, nullptr,
                                                         nullptr, m1_buf, NM);
  // s_m2a = scatter_m2a(P_m2a)
  edge_scatter<<<1024, 256, 0, stream>>>(m1_buf, m2a_src, m2a_dst, m2a_w, m2a_ea,
                                         We_m2a, sm2a, E_MA);

  // outputs
  final_add<<<NA, 128, 0, stream>>>(a2_buf, a_x, sm2a, g_m2a, b_m2a, out_a, NA);
  final_add<<<NM, 128, 0, stream>>>(m2_buf, m_x, sa2m, g_a2m, b_a2m, out_m, NM);
}